// Round 1
// baseline (98.206 us; speedup 1.0000x reference)
//
#include <hip/hip_runtime.h>
#include <math.h>

// ---- reference constants ----
#define NZV      50
#define NSTEPSV  50
static constexpr float F_DZ      = 1000.0f / 50.0f;   // dz = THICKNESS/NZ = 20
static constexpr float F_RMIN    = 0.8f;
static constexpr float F_RMAX    = 10.0f;
static constexpr float F_DEVT    = 15.0f;
// a_mack = 0.99^5 * 6/4  (double-evaluated, then float)
static constexpr float F_AMACK   = 1.4264850748500002f;
// log2(e)
static constexpr double D_LOG2E  = 1.4426950408889634;
// lat update: exp(-DILL_C * dt * LAMP * bulk) = 2^(K0 * bulk); DILL_C*40 = 0.1
static constexpr float F_K0      = (float)(-0.1 * D_LOG2E);
// bulk update: exp(-(A*lat+B)*z) = 2^(KA*z*lat) * 2^(KB*z)
static constexpr float F_KA      = (float)(-0.00075 * D_LOG2E);
static constexpr float F_KB      = (float)(-0.00005 * D_LOG2E);
// initial bulk: exp(-ALPHA0*z) = 2^(K_A0*z)
static constexpr float F_KA0     = (float)(-0.0005 * D_LOG2E);

#if __has_builtin(__builtin_amdgcn_exp2f)
#define EXP2F(x) __builtin_amdgcn_exp2f(x)
#else
#define EXP2F(x) exp2f(x)
#endif

__global__ __launch_bounds__(256) void resist_kernel(const float* __restrict__ img,
                                                     float* __restrict__ out, int n) {
    int idx = blockIdx.x * blockDim.x + threadIdx.x;
    if (idx >= n) return;

    const float I = img[idx];

    float t   = F_DEVT;   // remaining develop time
    float res = 0.0f;     // developed depth

    // Lazily compute rate(z_iz) and consume it immediately; rate>=0.8 means
    // each non-final step burns >=2.0s of the 15s budget -> loop exits in <=8
    // iterations, so slices 8..49 are never needed.
    for (int iz = 0; iz < NZV; ++iz) {
        const float z  = (float)((double)iz * (1000.0 / 49.0));  // linspace(0,1000,50)
        const float cB = I * EXP2F(F_KB * z);    // I * exp(-B*z)
        const float k1 = F_KA * z;               // per-step: bulk = cB * 2^(k1*lat)
        float bulk = I * EXP2F(F_KA0 * z);       // bulk_ini * exp(-ALPHA0*z)
        float lat  = 1.0f;

        #pragma unroll
        for (int s = 0; s < NSTEPSV; ++s) {
            lat *= EXP2F(F_K0 * bulk);
            if (s < NSTEPSV - 1)                 // final bulk update is dead
                bulk = cB * EXP2F(k1 * lat);
        }

        // Mack rate
        const float om  = 1.0f - lat;
        const float om2 = om * om;
        const float pm  = om2 * om2 * om;        // (1-lat)^5
        float rate = (F_AMACK + 1.0f) * pm / (F_AMACK + pm) * F_RMAX + F_RMIN;
        rate = fminf(fmaxf(rate, F_RMIN), F_RMAX);

        // development step (matches reference scan body exactly)
        const float cur = rate * t;
        if (cur <= F_DZ) {
            res += cur;
            break;                                // t = 0; all later steps are no-ops
        }
        res += F_DZ;
        t   -= F_DZ / rate;
    }

    out[idx] = res;
}

extern "C" void kernel_launch(void* const* d_in, const int* in_sizes, int n_in,
                              void* d_out, int out_size, void* d_ws, size_t ws_size,
                              hipStream_t stream) {
    const float* img = (const float*)d_in[0];
    float* out = (float*)d_out;
    const int n = in_sizes[0];               // 2*512*512 = 524288
    const int block = 256;
    const int grid = (n + block - 1) / block;
    resist_kernel<<<grid, block, 0, stream>>>(img, out, n);
}

// Round 2
// 62.022 us; speedup vs baseline: 1.5834x; 1.5834x over previous
//
#include <hip/hip_runtime.h>
#include <math.h>

// ---- reference constants ----
#define NZV      50
#define NSTEPSV  50
#define NSLICE   8        // proven upper bound: rate<=10 -> each full dev step
                          // consumes >=2.0s of the 15s budget -> <=8 slices used
#define KTAB     8192     // table resolution; interp err ~ F''*h^2/8 ~ 1e-5

static constexpr float F_DZ      = 1000.0f / 50.0f;   // dz = 20
static constexpr float F_RMIN    = 0.8f;
static constexpr float F_RMAX    = 10.0f;
static constexpr float F_DEVT    = 15.0f;
static constexpr float F_AMACK   = 1.4264850748500002f;  // 0.99^5 * 6/4
static constexpr double D_LOG2E  = 1.4426950408889634;
static constexpr float F_K0      = (float)(-0.1 * D_LOG2E);      // lat step
static constexpr float F_KA      = (float)(-0.00075 * D_LOG2E);  // bulk: A term
static constexpr float F_KB      = (float)(-0.00005 * D_LOG2E);  // bulk: B term
static constexpr float F_KA0     = (float)(-0.0005 * D_LOG2E);   // initial bulk

#if __has_builtin(__builtin_amdgcn_exp2f)
#define EXP2F(x) __builtin_amdgcn_exp2f(x)
#else
#define EXP2F(x) exp2f(x)
#endif

// Full per-sample resist simulation, identical arithmetic to the passing
// round-1 kernel, but with the 8 independent z-slice recurrences interleaved
// for ILP (this kernel runs at ~1 wave/SIMD, so ILP is the latency hider).
__device__ __forceinline__ float simulate(float I) {
    float lat[NSLICE], bulk[NSLICE], cB[NSLICE], k1[NSLICE];
    #pragma unroll
    for (int iz = 0; iz < NSLICE; ++iz) {
        const float z = (float)((double)iz * (1000.0 / 49.0));  // linspace(0,1000,50)
        cB[iz]   = I * EXP2F(F_KB * z);
        k1[iz]   = F_KA * z;
        bulk[iz] = I * EXP2F(F_KA0 * z);
        lat[iz]  = 1.0f;
    }
    for (int s = 0; s < NSTEPSV - 1; ++s) {
        #pragma unroll
        for (int iz = 0; iz < NSLICE; ++iz)
            lat[iz] *= EXP2F(F_K0 * bulk[iz]);
        #pragma unroll
        for (int iz = 0; iz < NSLICE; ++iz)
            bulk[iz] = cB[iz] * EXP2F(k1[iz] * lat[iz]);
    }
    #pragma unroll
    for (int iz = 0; iz < NSLICE; ++iz)           // final step (bulk update dead)
        lat[iz] *= EXP2F(F_K0 * bulk[iz]);

    float t = F_DEVT, res = 0.0f;
    #pragma unroll
    for (int iz = 0; iz < NSLICE; ++iz) {
        const float om  = 1.0f - lat[iz];
        const float om2 = om * om;
        const float pm  = om2 * om2 * om;          // (1-lat)^5
        float rate = (F_AMACK + 1.0f) * pm / (F_AMACK + pm) * F_RMAX + F_RMIN;
        rate = fminf(fmaxf(rate, F_RMIN), F_RMAX);
        const float cur = rate * t;
        if (cur <= F_DZ) { res += cur; break; }
        res += F_DZ;
        t   -= F_DZ / rate;
    }
    return res;
}

__global__ __launch_bounds__(256) void build_table(float* __restrict__ T) {
    int i = blockIdx.x * blockDim.x + threadIdx.x;
    if (i > KTAB) return;
    T[i] = simulate((float)i * (1.0f / (float)KTAB));
}

__global__ __launch_bounds__(256) void lookup_kernel(const float* __restrict__ img,
                                                     const float* __restrict__ T,
                                                     float* __restrict__ out, int n) {
    int idx = blockIdx.x * blockDim.x + threadIdx.x;
    if (idx >= n) return;
    const float x = img[idx] * (float)KTAB;        // I in [0,1) -> x in [0,KTAB)
    int j = (int)x;
    j = j < 0 ? 0 : (j > KTAB - 1 ? KTAB - 1 : j);
    const float f  = x - (float)j;
    const float t0 = T[j];
    const float t1 = T[j + 1];
    out[idx] = fmaf(f, t1 - t0, t0);               // lerp
}

// Fallback: direct per-pixel simulation (round-1 kernel) if ws too small.
__global__ __launch_bounds__(256) void resist_direct(const float* __restrict__ img,
                                                     float* __restrict__ out, int n) {
    int idx = blockIdx.x * blockDim.x + threadIdx.x;
    if (idx >= n) return;
    out[idx] = simulate(img[idx]);
}

extern "C" void kernel_launch(void* const* d_in, const int* in_sizes, int n_in,
                              void* d_out, int out_size, void* d_ws, size_t ws_size,
                              hipStream_t stream) {
    const float* img = (const float*)d_in[0];
    float* out = (float*)d_out;
    const int n = in_sizes[0];                     // 2*512*512 = 524288
    const int block = 256;
    const size_t tab_bytes = (size_t)(KTAB + 1) * sizeof(float);

    if (ws_size >= tab_bytes) {
        float* T = (float*)d_ws;
        build_table<<<(KTAB + block) / block, block, 0, stream>>>(T);
        lookup_kernel<<<(n + block - 1) / block, block, 0, stream>>>(img, T, out, n);
    } else {
        resist_direct<<<(n + block - 1) / block, block, 0, stream>>>(img, out, n);
    }
}